// Round 7
// baseline (157.111 us; speedup 1.0000x reference)
//
#include <hip/hip_runtime.h>

// Problem constants (inputs: (32,64,32,32) fp32; embed: (64,1024) fp32)
#define N_PIX  32768   // B*H*W
#define C_DIM  64
#define K_EMB  1024
#define HW     1024    // H*W
#define PIXB   32      // pixels per block (grid 1024)

// d_out layout (float32, concatenated in return order):
//   quantized_out (B,C,H,W) | loss | encoding_indices | perplexity
#define OUT_Q_OFF    0
#define OUT_LOSS_OFF 2097152
#define OUT_IDX_OFF  2097153
#define OUT_PERP_OFF 2129921

typedef __attribute__((ext_vector_type(8)))  __bf16 bf16x8;
typedef __attribute__((ext_vector_type(16))) float  f32x16;

// g_esplit: bf16x3 split of embed, fragment-packed:
//   [j][tile(32 codes)][s(k/16)][h(k8 half)][c32][e(8)] -> 3*65536 shorts = 384 KB
__device__ unsigned short g_esplit[3 * K_EMB * C_DIM];
__device__ uint4          g_eesplit[2 * K_EMB];  // ee-slice frags; [h][code], h=1 zero
__device__ float          g_ee[K_EMB];     // ||e_k||^2, fp32 fmaf chain (c-order)
__device__ unsigned int   g_counts[K_EMB];
__device__ float          g_lossAcc;
__device__ unsigned int   g_done;

__device__ __forceinline__ unsigned short f2bf(float f) {   // RNE f32->bf16
    unsigned u = __float_as_uint(f);
    unsigned r = u + 0x7FFFu + ((u >> 16) & 1u);
    return (unsigned short)(r >> 16);
}
__device__ __forceinline__ float bf2f(unsigned short b) {
    return __uint_as_float(((unsigned)b) << 16);
}
__device__ __forceinline__ unsigned long long pack_score(float d, int k) {
    unsigned int u = __float_as_uint(d);
    u = (u & 0x80000000u) ? ~u : (u | 0x80000000u);  // monotone map, negative-safe
    return ((unsigned long long)u << 32) | (unsigned int)k;
}
__device__ __forceinline__ uint4 pack8(const unsigned short* v) {
    uint4 u;
    u.x = (unsigned)v[0] | ((unsigned)v[1] << 16);
    u.y = (unsigned)v[2] | ((unsigned)v[3] << 16);
    u.z = (unsigned)v[4] | ((unsigned)v[5] << 16);
    u.w = (unsigned)v[6] | ((unsigned)v[7] << 16);
    return u;
}
// float top-2 (max) with index tracking
#define FUPD2(M1, K1, M2, K2, F, KK) { \
    if ((F) > M1) { M2 = M1; K2 = K1; M1 = (F); K1 = (KK); } \
    else if ((F) > M2) { M2 = (F); K2 = (KK); } }

// Split embed into bf16x3 fragment layout (uint4 stores) + ||e||^2 chain
// + ee-slice MFMA fragment (-0.5*||e||^2 split bf16x3 at K-elems 0..2).
__global__ void k_prep(const float* __restrict__ embed) {
    const int code = blockIdx.x * 64 + threadIdx.x;   // grid 16 x 64 -> 0..1023
    if (code == 0) { g_lossAcc = 0.f; g_done = 0u; }
    g_counts[code] = 0u;
    const int tile = code >> 5, c32 = code & 31;
    uint4* o = reinterpret_cast<uint4*>(g_esplit);
    float ee = 0.f;
#pragma unroll
    for (int s = 0; s < 4; ++s)
#pragma unroll
        for (int hh = 0; hh < 2; ++hh) {
            unsigned short b1[8], b2[8], b3[8];
#pragma unroll
            for (int e = 0; e < 8; ++e) {
                const float x = embed[(s * 16 + hh * 8 + e) * K_EMB + code];
                ee = fmaf(x, x, ee);                  // sequential c-order chain
                b1[e] = f2bf(x);
                const float r1 = x - bf2f(b1[e]);
                b2[e] = f2bf(r1);
                const float r2 = r1 - bf2f(b2[e]);
                b3[e] = f2bf(r2);
            }
            const int oi = tile * 256 + s * 64 + hh * 32 + c32;
            o[oi        ] = pack8(b1);
            o[oi +  8192] = pack8(b2);
            o[oi + 16384] = pack8(b3);
        }
    g_ee[code] = ee;
    // ee-slice fragment: -0.5*ee split bf16x3 at K elements 0,1,2 (h=0 half)
    const float v = -0.5f * ee;
    const unsigned short e1 = f2bf(v);
    const float r1 = v - bf2f(e1);
    const unsigned short e2 = f2bf(r1);
    const float r2 = r1 - bf2f(e2);
    const unsigned short e3 = f2bf(r2);
    g_eesplit[code] = make_uint4((unsigned)e1 | ((unsigned)e2 << 16),
                                 (unsigned)e3, 0u, 0u);
    g_eesplit[K_EMB + code] = make_uint4(0u, 0u, 0u, 0u);
}

// Main: 32 pixels x 1024 codes per block, 256 threads (4 waves).
// SWAPPED operands: A=X (stationary in regs), B=E (streamed, 1-deep prefetch).
// D: row=pixel=(rg&3)+8*(rg>>2)+4*h, col=code=ct*32+(lane&31). Lane-local
// per-(code-col,pixel) top-2 via fmed3/fmax with iter embedded in low 3 bits;
// exact fp32 rescore (verified) decides. k_scalar fused via last-block-done.
__global__ __launch_bounds__(256, 1) void k_main(
    const float* __restrict__ inp, const float* __restrict__ embed,
    float* __restrict__ out_q, float* __restrict__ out_idx,
    float* __restrict__ out_loss, float* __restrict__ out_perp) {

    __shared__ float    x_raw[C_DIM * PIXB];       // 8 KB raw fp32 tile [c][p]
    __shared__ uint4    xfrag[3 * 4 * 2 * PIXB];   // 12 KB [j][s][h][p]
    __shared__ unsigned cand1[PIXB * 128];         // 16 KB [pixel][w*32+lane]
    __shared__ unsigned cand2[PIXB * 128];         // 16 KB
    __shared__ uint4    pxm[PIXB][8];              // 4 KB stage-A partials
    __shared__ int      ksel[PIXB];
    __shared__ float    lred[4];
    __shared__ float    bdist;
    __shared__ unsigned lastFlag;

    const int tid = threadIdx.x;
    const int n0  = blockIdx.x * PIXB;
    const int b   = n0 >> 10;
    const int hw0 = n0 & 1023;
    const float* __restrict__ xg = inp + b * (C_DIM * HW) + hw0;

    // ---- stage 1: coalesced raw tile load -> LDS (512 float4, 256 thr x 2)
#pragma unroll
    for (int i = 0; i < 2; ++i) {
        const int F = tid + i * 256;               // float4 index 0..511
        const int c = F >> 3, p4 = (F & 7) << 2;
        *reinterpret_cast<float4*>(&x_raw[F << 2]) =
            *reinterpret_cast<const float4*>(xg + c * HW + p4);
    }
    __syncthreads();

    // ---- stage 2: bf16x3 split into fragment layout + ||x||^2 partial
    float sx2 = 0.f;
    {
        const int s = tid >> 6, hh = (tid >> 5) & 1, p = tid & 31;  // 256 slots
        unsigned short b1[8], b2[8], b3[8];
#pragma unroll
        for (int e = 0; e < 8; ++e) {
            const float x = x_raw[(s * 16 + hh * 8 + e) * PIXB + p];
            sx2 = fmaf(x, x, sx2);
            b1[e] = f2bf(x);
            const float r1 = x - bf2f(b1[e]);
            b2[e] = f2bf(r1);
            const float r2 = r1 - bf2f(b2[e]);
            b3[e] = f2bf(r2);
        }
        const int fi = (s * 2 + hh) * PIXB + p;    // within one j-plane (8*PIXB)
        xfrag[fi            ] = pack8(b1);
        xfrag[fi + 8 * PIXB ] = pack8(b2);
        xfrag[fi + 16 * PIXB] = pack8(b3);
    }
    for (int off = 32; off; off >>= 1) sx2 += __shfl_down(sx2, off, 64);
    if ((tid & 63) == 0) lred[tid >> 6] = sx2;
    __syncthreads();

    // ---- distance GEMM, swapped operands
    const int w   = tid >> 6;                      // wave 0..3
    const int ln  = tid & 63;
    const int c31 = ln & 31;
    const int h   = ln >> 5;
    const uint4* __restrict__ eg = reinterpret_cast<const uint4*>(g_esplit);
    const int abase = h * 32 + c31;
    const uint4 bones = make_uint4(h ? 0u : 0x3F803F80u, h ? 0u : 0x00003F80u, 0u, 0u);

#define LOADE(DST, DSTE, CT) { \
    const int bb = (CT) * 256 + abase; \
    _Pragma("unroll") for (int s = 0; s < 4; ++s) { \
        DST[s]     = eg[bb + s * 64]; \
        DST[4 + s] = eg[bb +  8192 + s * 64]; \
        DST[8 + s] = eg[bb + 16384 + s * 64]; } \
    DSTE = g_eesplit[h * K_EMB + (CT) * 32 + c31]; }

    // prefetch r=0 E-frags, then stationary X frags (latency overlaps ds_reads)
    uint4 pA[12], pAe, pB[12], pBe;
    LOADE(pA, pAe, w)

    uint4 xa0[4], xa1[4], xa2[4];
#pragma unroll
    for (int s = 0; s < 4; ++s) {
        xa0[s] = xfrag[(     s * 2 + h) * PIXB + c31];
        xa1[s] = xfrag[( 8 + s * 2 + h) * PIXB + c31];
        xa2[s] = xfrag[(16 + s * 2 + h) * PIXB + c31];
    }

    float m1[16], m2[16];
#pragma unroll
    for (int rg = 0; rg < 16; ++rg) { m1[rg] = -INFINITY; m2[rg] = -INFINITY; }

#define MFMA1(AF, BF) \
    acc = __builtin_amdgcn_mfma_f32_32x32x16_bf16( \
        __builtin_bit_cast(bf16x8, AF), __builtin_bit_cast(bf16x8, BF), acc, 0, 0, 0);

// one r-step: prefetch R+1 E-frags into NXT, compute with CUR, fold with iter R
#define STEP(CUR, CURE, NXT, NXTE, R) { \
    { const int rn = (R) < 7 ? (R) + 1 : 7; LOADE(NXT, NXTE, rn * 4 + w) } \
    f32x16 acc = {}; \
    MFMA1(bones, CURE) \
    _Pragma("unroll") for (int s = 0; s < 4; ++s) { MFMA1(xa0[s], CUR[s]) }     /* x0*e0 */ \
    _Pragma("unroll") for (int s = 0; s < 4; ++s) { MFMA1(xa1[s], CUR[s]) }     /* x1*e0 */ \
    _Pragma("unroll") for (int s = 0; s < 4; ++s) { MFMA1(xa2[s], CUR[s]) }     /* x2*e0 */ \
    _Pragma("unroll") for (int s = 0; s < 4; ++s) { MFMA1(xa0[s], CUR[4 + s]) } /* x0*e1 */ \
    _Pragma("unroll") for (int s = 0; s < 4; ++s) { MFMA1(xa1[s], CUR[4 + s]) } /* x1*e1 */ \
    _Pragma("unroll") for (int s = 0; s < 4; ++s) { MFMA1(xa0[s], CUR[8 + s]) } /* x0*e2 */ \
    _Pragma("unroll") for (int rg = 0; rg < 16; ++rg) { \
        const unsigned cu = (__float_as_uint(acc[rg]) & 0xFFFFFFF8u) | (unsigned)(R); \
        const float cf = __uint_as_float(cu); \
        m2[rg] = __builtin_amdgcn_fmed3f(m1[rg], m2[rg], cf); \
        m1[rg] = fmaxf(m1[rg], cf); \
    } }

#pragma unroll 1
    for (int rr = 0; rr < 4; ++rr) {
        STEP(pA, pAe, pB, pBe, 2 * rr)
        STEP(pB, pBe, pA, pAe, 2 * rr + 1)
    }
#undef STEP
#undef MFMA1
#undef LOADE

    // ---- write per-cell top-2 to LDS: [pixel][w*32+lane]
#pragma unroll
    for (int rg = 0; rg < 16; ++rg) {
        const int px = (rg & 3) + 8 * (rg >> 2) + 4 * h;
        cand1[px * 128 + w * 32 + c31] = __float_as_uint(m1[rg]);
        cand2[px * 128 + w * 32 + c31] = __float_as_uint(m2[rg]);
    }
    __syncthreads();

    // ---- stage A: 8 threads/pixel, each scans 16 cells (x2 arrays)
    {
        const int px = tid >> 3, sl = tid & 7;
        const int base = px * 128 + sl * 16;
        float a1 = -INFINITY, a2 = -INFINITY; int k1 = 0, k2 = 0;
#pragma unroll
        for (int i = 0; i < 16; ++i) {
            const int idx = sl * 16 + i;
            const int klo = (idx >> 5) * 32 + (idx & 31);   // w*32 + lane
            unsigned u = cand1[base + i];
            int kk = (int)((u & 7u) * 128u) + klo;          // (r*4+w)*32+lane
            float f = __uint_as_float(u);
            FUPD2(a1, k1, a2, k2, f, kk)
            u = cand2[base + i];
            kk = (int)((u & 7u) * 128u) + klo;
            f = __uint_as_float(u);
            FUPD2(a1, k1, a2, k2, f, kk)
        }
        pxm[px][sl] = make_uint4(__float_as_uint(a1), (unsigned)k1,
                                 __float_as_uint(a2), (unsigned)k2);
    }
    __syncthreads();

    // ---- stage B: final top-2 + exact fp32 rescore (verified op order)
    if (tid < PIXB) {
        float a1 = -INFINITY, a2 = -INFINITY; int k1 = 0, k2 = 0;
#pragma unroll
        for (int sl = 0; sl < 8; ++sl) {
            const uint4 v = pxm[tid][sl];
            FUPD2(a1, k1, a2, k2, __uint_as_float(v.x), (int)v.y)
            FUPD2(a1, k1, a2, k2, __uint_as_float(v.z), (int)v.w)
        }
        // exact fp32 rescore: dot = sequential fmaf over c; dist = fmaf(-2,dot,ee)
        float d1 = 0.f, d2 = 0.f;
        const float* xcol = x_raw + tid;
#pragma unroll 8
        for (int c = 0; c < C_DIM; ++c) {
            const float xv = xcol[c * PIXB];
            d1 = fmaf(xv, embed[c * K_EMB + k1], d1);
            d2 = fmaf(xv, embed[c * K_EMB + k2], d2);
        }
        const float dist1 = fmaf(-2.f, d1, g_ee[k1]);
        const float dist2 = fmaf(-2.f, d2, g_ee[k2]);
        const unsigned long long s1 = pack_score(dist1, k1);
        const unsigned long long s2 = pack_score(dist2, k2);
        const int   k     = (s1 < s2) ? k1 : k2;
        const float distw = (s1 < s2) ? dist1 : dist2;   // exact winner distance
        ksel[tid] = k;
        out_idx[n0 + tid] = (float)k;
        atomicAdd(g_counts + k, 1u);
        // 32-lane sum (width 32: lanes 32..63 inactive here!)
        float dist = distw;    // ||x-q||^2 = ||x||^2 + dist
        for (int off = 16; off; off >>= 1) dist += __shfl_down(dist, off, 32);
        if (tid == 0) bdist = dist;
    }
    __syncthreads();

    // ---- quantize gather + coalesced store (512 float4, 256 thr x 2)
#pragma unroll
    for (int i = 0; i < 2; ++i) {
        const int F = tid + i * 256;               // 0..511
        const int c = F >> 3, p0 = (F & 7) << 2;
        float* oq = out_q + b * (C_DIM * HW) + c * HW + hw0 + p0;
        const float* er = embed + c * K_EMB;
        float4 q;
        q.x = er[ksel[p0 + 0]];
        q.y = er[ksel[p0 + 1]];
        q.z = er[ksel[p0 + 2]];
        q.w = er[ksel[p0 + 3]];
        *reinterpret_cast<float4*>(oq) = q;
    }

    // ---- loss accumulate + last-block-done: fused scalar epilogue
    if (tid == 0) {
        atomicAdd(&g_lossAcc, lred[0] + lred[1] + lred[2] + lred[3] + bdist);
        __threadfence();
        lastFlag = (atomicAdd(&g_done, 1u) == (unsigned)(gridDim.x - 1)) ? 1u : 0u;
    }
    __syncthreads();
    if (lastFlag) {   // uniform across block
        float t = 0.f;
#pragma unroll
        for (int i = 0; i < 4; ++i) {
            const unsigned c = atomicAdd(&g_counts[tid * 4 + i], 0u);  // device-coherent read
            const float p = (float)c * (1.0f / (float)N_PIX);
            t += p * logf(p + 1e-10f);
        }
        for (int off = 32; off; off >>= 1) t += __shfl_down(t, off, 64);
        if (ln == 0) lred[w] = t;
        __syncthreads();
        if (tid == 0) {
            const float s  = lred[0] + lred[1] + lred[2] + lred[3];
            const float la = atomicAdd(&g_lossAcc, 0.f);
            *out_perp = expf(-s);
            *out_loss = 0.25f * la * (1.0f / (float)(N_PIX * C_DIM));
        }
    }
}

extern "C" void kernel_launch(void* const* d_in, const int* in_sizes, int n_in,
                              void* d_out, int out_size, void* d_ws, size_t ws_size,
                              hipStream_t stream) {
    const float* inp   = (const float*)d_in[0];
    const float* embed = (const float*)d_in[1];
    float* out = (float*)d_out;

    k_prep<<<dim3(16), dim3(64), 0, stream>>>(embed);
    k_main<<<dim3(N_PIX / PIXB), dim3(256), 0, stream>>>(
        inp, embed, out + OUT_Q_OFF, out + OUT_IDX_OFF,
        out + OUT_LOSS_OFF, out + OUT_PERP_OFF);
}

// Round 10
// 142.586 us; speedup vs baseline: 1.1019x; 1.1019x over previous
//
#include <hip/hip_runtime.h>

// Problem constants (inputs: (32,64,32,32) fp32; embed: (64,1024) fp32)
#define N_PIX  32768   // B*H*W
#define C_DIM  64
#define K_EMB  1024
#define HW     1024    // H*W
#define PIXB   128     // pixels per block (grid 256 -> 1 block/CU)

// d_out layout (float32, concatenated in return order):
//   quantized_out (B,C,H,W) | loss | encoding_indices | perplexity
#define OUT_Q_OFF    0
#define OUT_LOSS_OFF 2097152
#define OUT_IDX_OFF  2097153
#define OUT_PERP_OFF 2129921

typedef __attribute__((ext_vector_type(8)))  __bf16 bf16x8;
typedef __attribute__((ext_vector_type(16))) float  f32x16;

// g_esplit: bf16x3 split of embed, A-fragment-packed:
//   [j][tile(32 codes)][s(k/16)][h(k8 half)][c32][e(8)] -> 3*65536 shorts = 384 KB
__device__ unsigned short g_esplit[3 * K_EMB * C_DIM];
__device__ uint4          g_eesplit[2 * K_EMB];  // ee-slice A frags; [h][code], h=1 zero
__device__ float          g_ee[K_EMB];     // ||e_k||^2, fp32 fmaf chain (c-order)
__device__ unsigned int   g_counts[K_EMB];
__device__ float          g_lossAcc;
__device__ unsigned int   g_done;

__device__ __forceinline__ unsigned short f2bf(float f) {   // RNE f32->bf16
    unsigned u = __float_as_uint(f);
    unsigned r = u + 0x7FFFu + ((u >> 16) & 1u);
    return (unsigned short)(r >> 16);
}
__device__ __forceinline__ float bf2f(unsigned short b) {
    return __uint_as_float(((unsigned)b) << 16);
}
__device__ __forceinline__ unsigned long long pack_score(float d, int k) {
    unsigned int u = __float_as_uint(d);
    u = (u & 0x80000000u) ? ~u : (u | 0x80000000u);  // monotone map, negative-safe
    return ((unsigned long long)u << 32) | (unsigned int)k;
}
__device__ __forceinline__ uint4 pack8(const unsigned short* v) {
    uint4 u;
    u.x = (unsigned)v[0] | ((unsigned)v[1] << 16);
    u.y = (unsigned)v[2] | ((unsigned)v[3] << 16);
    u.z = (unsigned)v[4] | ((unsigned)v[5] << 16);
    u.w = (unsigned)v[6] | ((unsigned)v[7] << 16);
    return u;
}
// float top-2 (max) with index tracking
#define FUPD2(M1, K1, M2, K2, F, KK) { \
    if ((F) > M1) { M2 = M1; K2 = K1; M1 = (F); K1 = (KK); } \
    else if ((F) > M2) { M2 = (F); K2 = (KK); } }

// Split embed into bf16x3 fragment layout (uint4 stores) + ||e||^2 chain
// + ee-slice MFMA fragment (-0.5*||e||^2 split bf16x3 at K-elems 0..2).
__global__ void k_prep(const float* __restrict__ embed) {
    const int code = blockIdx.x * 64 + threadIdx.x;   // grid 16 x 64 -> 0..1023
    if (code == 0) { g_lossAcc = 0.f; g_done = 0u; }
    g_counts[code] = 0u;
    const int tile = code >> 5, c32 = code & 31;
    uint4* o = reinterpret_cast<uint4*>(g_esplit);
    float ee = 0.f;
#pragma unroll
    for (int s = 0; s < 4; ++s)
#pragma unroll
        for (int hh = 0; hh < 2; ++hh) {
            unsigned short b1[8], b2[8], b3[8];
#pragma unroll
            for (int e = 0; e < 8; ++e) {
                const float x = embed[(s * 16 + hh * 8 + e) * K_EMB + code];
                ee = fmaf(x, x, ee);                  // sequential c-order chain
                b1[e] = f2bf(x);
                const float r1 = x - bf2f(b1[e]);
                b2[e] = f2bf(r1);
                const float r2 = r1 - bf2f(b2[e]);
                b3[e] = f2bf(r2);
            }
            const int oi = tile * 256 + s * 64 + hh * 32 + c32;
            o[oi        ] = pack8(b1);
            o[oi +  8192] = pack8(b2);
            o[oi + 16384] = pack8(b3);
        }
    g_ee[code] = ee;
    // ee-slice fragment: -0.5*ee split bf16x3 at K elements 0,1,2 (h=0 half)
    const float v = -0.5f * ee;
    const unsigned short e1 = f2bf(v);
    const float r1 = v - bf2f(e1);
    const unsigned short e2 = f2bf(r1);
    const float r2 = r1 - bf2f(e2);
    const unsigned short e3 = f2bf(r2);
    g_eesplit[code] = make_uint4((unsigned)e1 | ((unsigned)e2 << 16),
                                 (unsigned)e3, 0u, 0u);
    g_eesplit[K_EMB + code] = make_uint4(0u, 0u, 0u, 0u);
}

// Main: 128 pixels x 1024 codes per block, 256 threads (4 waves), grid 256
// (1 block/CU). A=E (streamed once per block), B=X (LDS). Each r-step: 13 E
// loads feed 4 pt-subtiles x 25 MFMAs. Exact per-lane top-2; exact fp32
// rescore decides. R8/R9 BUG FIXED: stage-1 must load 2048 float4 (8 iters)
// at PIXB=128 — the 4-iter version left channels 32..63 of x_raw garbage.
__global__ __launch_bounds__(256, 1) void k_main(
    const float* __restrict__ inp, const float* __restrict__ embed,
    float* __restrict__ out_q, float* __restrict__ out_idx,
    float* __restrict__ out_loss, float* __restrict__ out_perp) {

    __shared__ float    x_raw[C_DIM * PIXB];       // 32 KB raw fp32 tile [c][p]
    __shared__ uint4    xfrag[3 * 4 * 2 * PIXB];   // 48 KB [j][s][h][p]
    __shared__ float    red1[4][PIXB];             // per-wave top-1 score
    __shared__ float    red2[4][PIXB];             // per-wave top-2 score
    __shared__ int      redk1[4][PIXB];            // per-wave top-1 code
    __shared__ int      redk2[4][PIXB];            // per-wave top-2 code
    __shared__ int      ksel[PIXB];
    __shared__ float    lred[4];
    __shared__ float    lred2[2];
    __shared__ unsigned lastFlag;

    const int tid = threadIdx.x;
    const int n0  = blockIdx.x * PIXB;
    const int b   = n0 >> 10;
    const int hw0 = n0 & 1023;
    const float* __restrict__ xg = inp + b * (C_DIM * HW) + hw0;

    // ---- stage 1: coalesced raw tile load -> LDS (2048 float4, 256 thr x 8)
#pragma unroll
    for (int i = 0; i < 8; ++i) {
        const int F = tid + i * 256;               // float4 index 0..2047
        const int c = F >> 5, p4 = (F & 31) << 2;  // c 0..63, p4 0..124
        *reinterpret_cast<float4*>(&x_raw[F << 2]) =
            *reinterpret_cast<const float4*>(xg + c * HW + p4);
    }
    __syncthreads();

    // ---- stage 2: bf16x3 split into fragment layout + ||x||^2 partial
    float sx2 = 0.f;
#pragma unroll
    for (int cc = 0; cc < 4; ++cc) {
        const int cid = tid + cc * 256;            // 0..1023 = (s,hh,p)
        const int s = cid >> 8, hh = (cid >> 7) & 1, p = cid & 127;
        unsigned short b1[8], b2[8], b3[8];
#pragma unroll
        for (int e = 0; e < 8; ++e) {
            const float x = x_raw[(s * 16 + hh * 8 + e) * PIXB + p];
            sx2 = fmaf(x, x, sx2);
            b1[e] = f2bf(x);
            const float r1 = x - bf2f(b1[e]);
            b2[e] = f2bf(r1);
            const float r2 = r1 - bf2f(b2[e]);
            b3[e] = f2bf(r2);
        }
        const int fi = (s * 2 + hh) * PIXB + p;    // within one j-plane (8*PIXB)
        xfrag[fi            ] = pack8(b1);
        xfrag[fi + 8 * PIXB ] = pack8(b2);
        xfrag[fi + 16 * PIXB] = pack8(b3);
    }
    for (int off = 32; off; off >>= 1) sx2 += __shfl_down(sx2, off, 64);
    if ((tid & 63) == 0) lred[tid >> 6] = sx2;
    __syncthreads();

    // ---- distance GEMM + exact per-lane top-2 (score = dot - ee/2, maximize)
    const int w   = tid >> 6;                      // wave 0..3
    const int ln  = tid & 63;
    const int c31 = ln & 31;
    const int h   = ln >> 5;
    const uint4* __restrict__ eg = reinterpret_cast<const uint4*>(g_esplit);
    const int abase = h * 32 + c31;
    const int kbase = w * 32 + 4 * h;              // + r*128 + (rg&3) + 8*(rg>>2)
    const uint4 bones = make_uint4(h ? 0u : 0x3F803F80u, h ? 0u : 0x00003F80u, 0u, 0u);

    float m1[4], m2[4];                            // per-pt top-2 (static idx)
    int   k1[4], k2[4];
#pragma unroll
    for (int pt = 0; pt < 4; ++pt) {
        m1[pt] = -INFINITY; m2[pt] = -INFINITY; k1[pt] = 0; k2[pt] = 0;
    }

#define MFMA1(AF, BF) \
    acc = __builtin_amdgcn_mfma_f32_32x32x16_bf16( \
        __builtin_bit_cast(bf16x8, AF), __builtin_bit_cast(bf16x8, BF), acc, 0, 0, 0);

#pragma unroll 1
    for (int r = 0; r < 8; ++r) {
        const int ct = r * 4 + w;                  // this wave's code tile 0..31
        const int b0 = ct * 256 + abase;
        // A fragments for this tile: j0, j1, j2, ee (13 x uint4, once per step)
        uint4 ae0[4], ae1[4], a2[4], aee;
#pragma unroll
        for (int s = 0; s < 4; ++s) {
            ae0[s] = eg[b0 + s * 64];
            ae1[s] = eg[b0 + 8192 + s * 64];
            a2[s]  = eg[b0 + 16384 + s * 64];
        }
        aee = g_eesplit[h * K_EMB + ct * 32 + c31];

#pragma unroll
        for (int pt = 0; pt < 4; ++pt) {           // 4 pixel sub-tiles per step
            const int pb = pt * 32 + c31;
            uint4 bx0[4], bx1[4], bx2[4];
#pragma unroll
            for (int s = 0; s < 4; ++s) bx0[s] = xfrag[(     s * 2 + h) * PIXB + pb];
#pragma unroll
            for (int s = 0; s < 4; ++s) bx1[s] = xfrag[( 8 + s * 2 + h) * PIXB + pb];
#pragma unroll
            for (int s = 0; s < 4; ++s) bx2[s] = xfrag[(16 + s * 2 + h) * PIXB + pb];
            f32x16 acc = {};
            MFMA1(aee, bones)
#pragma unroll
            for (int s = 0; s < 4; ++s) { MFMA1(ae0[s], bx0[s]) }
#pragma unroll
            for (int s = 0; s < 4; ++s) { MFMA1(ae1[s], bx0[s]) }
#pragma unroll
            for (int s = 0; s < 4; ++s) { MFMA1(ae0[s], bx1[s]) }
#pragma unroll
            for (int s = 0; s < 4; ++s) { MFMA1(ae1[s], bx1[s]) }
#pragma unroll
            for (int s = 0; s < 4; ++s) { MFMA1(ae0[s], bx2[s]) }
#pragma unroll
            for (int s = 0; s < 4; ++s) { MFMA1(a2[s],  bx0[s]) }
            // exact top-2 fold: score cf, code kk (r,rg compile-time consts)
#pragma unroll
            for (int rg = 0; rg < 16; ++rg) {
                const float cf = acc[rg];
                const int   kk = kbase + r * 128 + (rg & 3) + 8 * (rg >> 2);
                const bool  c1 = cf > m1[pt];
                const bool  c2 = cf > m2[pt];
                m2[pt] = __builtin_amdgcn_fmed3f(m1[pt], m2[pt], cf);
                k2[pt] = c1 ? k1[pt] : (c2 ? kk : k2[pt]);
                m1[pt] = fmaxf(m1[pt], cf);
                k1[pt] = c1 ? kk : k1[pt];
            }
        }
    }
#undef MFMA1

    // ---- combine lane halves (disjoint codes, same pixel): exact top-2 merge
#pragma unroll
    for (int pt = 0; pt < 4; ++pt) {
        const float o1  = __shfl_xor(m1[pt], 32, 64);
        const int   ok1 = __shfl_xor(k1[pt], 32, 64);
        const float o2  = __shfl_xor(m2[pt], 32, 64);
        const int   ok2 = __shfl_xor(k2[pt], 32, 64);
        const bool  c1 = o1 > m1[pt];
        const float t1 = c1 ? o1 : m1[pt];  const int tk1 = c1 ? ok1 : k1[pt];
        const float ts = c1 ? m1[pt] : o1;  const int tks = c1 ? k1[pt] : ok1;
        const bool  c2 = o2 > m2[pt];
        const float tc = c2 ? o2 : m2[pt];  const int tkc = c2 ? ok2 : k2[pt];
        const bool  c3 = tc > ts;
        const float t2 = c3 ? tc : ts;      const int tk2 = c3 ? tkc : tks;
        if (ln < 32) {
            red1[w][pt * 32 + c31] = t1;  redk1[w][pt * 32 + c31] = tk1;
            red2[w][pt * 32 + c31] = t2;  redk2[w][pt * 32 + c31] = tk2;
        }
    }
    __syncthreads();

    // ---- final top-2 across 4 waves + exact fp32 rescore (verified op order)
    if (tid < PIXB) {
        float a1 = -INFINITY, a2 = -INFINITY; int k1f = 0, k2f = 0;
#pragma unroll
        for (int wv = 0; wv < 4; ++wv) {
            FUPD2(a1, k1f, a2, k2f, red1[wv][tid], redk1[wv][tid])
            FUPD2(a1, k1f, a2, k2f, red2[wv][tid], redk2[wv][tid])
        }
        // exact fp32 rescore: dot = sequential fmaf over c; dist = fmaf(-2,dot,ee)
        float d1 = 0.f, d2 = 0.f;
        const float* xcol = x_raw + tid;
#pragma unroll 8
        for (int c = 0; c < C_DIM; ++c) {
            const float xv = xcol[c * PIXB];
            d1 = fmaf(xv, embed[c * K_EMB + k1f], d1);
            d2 = fmaf(xv, embed[c * K_EMB + k2f], d2);
        }
        const float dist1 = fmaf(-2.f, d1, g_ee[k1f]);
        const float dist2 = fmaf(-2.f, d2, g_ee[k2f]);
        const unsigned long long s1 = pack_score(dist1, k1f);
        const unsigned long long s2 = pack_score(dist2, k2f);
        const int   k     = (s1 < s2) ? k1f : k2f;
        const float distw = (s1 < s2) ? dist1 : dist2;   // exact winner distance
        ksel[tid] = k;
        out_idx[n0 + tid] = (float)k;
        atomicAdd(g_counts + k, 1u);
        float dist = distw;    // ||x-q||^2 = ||x||^2 + dist
        for (int off = 32; off; off >>= 1) dist += __shfl_down(dist, off, 64);
        if (ln == 0) lred2[w] = dist;   // waves 0,1 only (tid<128)
    }
    __syncthreads();

    // ---- quantize gather + coalesced store (2048 float4, 256 thr x 8)
#pragma unroll
    for (int i = 0; i < 8; ++i) {
        const int F = tid + i * 256;               // 0..2047
        const int c = F >> 5, p0 = (F & 31) << 2;
        float* oq = out_q + b * (C_DIM * HW) + c * HW + hw0 + p0;
        const float* er = embed + c * K_EMB;
        float4 q;
        q.x = er[ksel[p0 + 0]];
        q.y = er[ksel[p0 + 1]];
        q.z = er[ksel[p0 + 2]];
        q.w = er[ksel[p0 + 3]];
        *reinterpret_cast<float4*>(oq) = q;
    }

    // ---- loss accumulate + last-block-done fused scalar epilogue (R7-verified)
    if (tid == 0) {
        atomicAdd(&g_lossAcc, lred[0] + lred[1] + lred[2] + lred[3]
                              + lred2[0] + lred2[1]);
        __threadfence();
        lastFlag = (atomicAdd(&g_done, 1u) == (unsigned)(gridDim.x - 1)) ? 1u : 0u;
    }
    __syncthreads();
    if (lastFlag) {   // uniform across block
        float t = 0.f;
#pragma unroll
        for (int i = 0; i < 4; ++i) {
            const unsigned c = atomicAdd(&g_counts[tid * 4 + i], 0u);  // coherent read
            const float p = (float)c * (1.0f / (float)N_PIX);
            t += p * logf(p + 1e-10f);
        }
        for (int off = 32; off; off >>= 1) t += __shfl_down(t, off, 64);
        if (ln == 0) lred[w] = t;
        __syncthreads();
        if (tid == 0) {
            const float s  = lred[0] + lred[1] + lred[2] + lred[3];
            const float la = atomicAdd(&g_lossAcc, 0.f);
            *out_perp = expf(-s);
            *out_loss = 0.25f * la * (1.0f / (float)(N_PIX * C_DIM));
        }
    }
}

extern "C" void kernel_launch(void* const* d_in, const int* in_sizes, int n_in,
                              void* d_out, int out_size, void* d_ws, size_t ws_size,
                              hipStream_t stream) {
    const float* inp   = (const float*)d_in[0];
    const float* embed = (const float*)d_in[1];
    float* out = (float*)d_out;

    k_prep<<<dim3(16), dim3(64), 0, stream>>>(embed);
    k_main<<<dim3(N_PIX / PIXB), dim3(256), 0, stream>>>(
        inp, embed, out + OUT_Q_OFF, out + OUT_IDX_OFF,
        out + OUT_LOSS_OFF, out + OUT_PERP_OFF);
}